// Round 15
// baseline (207.408 us; speedup 1.0000x reference)
//
#include <hip/hip_runtime.h>
#include <hip/hip_bf16.h>
#include <stdint.h>

#define DM 1024
#define SZ ((size_t)8192*1024)      // elems of one [8192][1024] matrix (2^23)
#define WSZ ((size_t)1024*1024)     // elems of one [1024][1024] weight

typedef float  f32x2  __attribute__((ext_vector_type(2)));
typedef float  f32x4  __attribute__((ext_vector_type(4)));
typedef float  f32x16 __attribute__((ext_vector_type(16)));
typedef __bf16 bf16x8 __attribute__((ext_vector_type(8)));
typedef __bf16 bf16x2 __attribute__((ext_vector_type(2)));
typedef short  s16x8  __attribute__((ext_vector_type(8)));
typedef unsigned int u32;
typedef unsigned int u32x4 __attribute__((ext_vector_type(4)));

typedef const __attribute__((address_space(1))) void* gas_ptr;
typedef __attribute__((address_space(3))) void* las_ptr;

static __device__ __forceinline__ f32x4 mfma16(s16x8 a, s16x8 b, f32x4 c){
  return __builtin_amdgcn_mfma_f32_16x16x32_bf16(
      __builtin_bit_cast(bf16x8, a), __builtin_bit_cast(bf16x8, b), c, 0, 0, 0);
}
static __device__ __forceinline__ f32x16 mfma32(s16x8 a, s16x8 b, f32x16 c){
  return __builtin_amdgcn_mfma_f32_32x32x16_bf16(
      __builtin_bit_cast(bf16x8, a), __builtin_bit_cast(bf16x8, b), c, 0, 0, 0);
}

// packed f32x2 -> bf16x2 (compiler emits v_cvt_pk_bf16_f32, RNE)
static __device__ __forceinline__ u32 pack2(float a, float b){
  bf16x2 v = { (__bf16)a, (__bf16)b };
  return __builtin_bit_cast(u32, v);
}
static __device__ __forceinline__ short f2bf(float f){
  __bf16 v = (__bf16)f;
  return __builtin_bit_cast(short, v);
}

static __device__ __forceinline__ void gload_lds16(void* l, const void* g){
  __builtin_amdgcn_global_load_lds((gas_ptr)g, (las_ptr)l, 16, 0, 0);
}

#define QSCALE 0.1803368801111444f   /* 0.125 * log2(e): folded into Wq */

// ---------------- conversion kernels ----------------

// q/k/v fp32 -> bf16 at ws[0..3SZ); Wout fp32 -> bf16 at ws[6SZ+3WSZ).
// 16 elems/thread: grid 6400 x 256 x 16 = 3*SZ + WSZ exactly.
__global__ void convert_misc(const float* __restrict__ q, const float* __restrict__ k,
                             const float* __restrict__ v, const float* __restrict__ wo,
                             short* __restrict__ ws){
  size_t c = (size_t)blockIdx.x*blockDim.x + threadIdx.x;   // 16-elem chunk id
  const size_t n16_in = 3*(SZ/16);                          // 3 * 2^19
  const float* src; short* dst;
  if (c < n16_in){
    int s = (int)(c >> 19);                 // SZ/16 = 2^19
    size_t off = c*16 - ((size_t)s << 23);
    src = (s==0 ? q : (s==1 ? k : v)) + off;
    dst = ws + c*16;
  } else {
    size_t off = (c - n16_in)*16;
    src = wo + off;
    dst = ws + 6*SZ + 3*WSZ + off;
  }
  float4 a = *(const float4*)src;
  float4 b = *(const float4*)(src + 4);
  float4 e = *(const float4*)(src + 8);
  float4 f = *(const float4*)(src + 12);
  uint4 o0, o1;
  o0.x = pack2(a.x, a.y); o0.y = pack2(a.z, a.w);
  o0.z = pack2(b.x, b.y); o0.w = pack2(b.z, b.w);
  o1.x = pack2(e.x, e.y); o1.y = pack2(e.z, e.w);
  o1.z = pack2(f.x, f.y); o1.w = pack2(f.z, f.w);
  *(uint4*)dst = o0;
  *(uint4*)(dst + 8) = o1;
}

// Wq/Wk/Wv [16][1024][64] -> Bt[n=h*64+k][d] bf16; Wq scaled by QSCALE
__global__ void convert_wqkv(const float* __restrict__ wq, const float* __restrict__ wk,
                             const float* __restrict__ wv, short* __restrict__ ws){
  __shared__ float tile[64][65];
  int bid = blockIdx.x;
  int sel = bid >> 8;          // 0..2
  int h   = (bid >> 4) & 15;
  int dt  = bid & 15;
  const float* W = sel==0 ? wq : (sel==1 ? wk : wv);
  float sc = sel==0 ? QSCALE : 1.0f;
  short* Bt = ws + 6*SZ + (size_t)sel*WSZ;
  int tid = threadIdx.x;
  int r = tid >> 4, c4 = (tid & 15)*4;
  int d0 = dt*64;
  #pragma unroll
  for (int i=0;i<4;i++){
    int d = r + i*16;
    float4 vv = *(const float4*)&W[(size_t)h*65536 + (size_t)(d0+d)*64 + c4];
    tile[d][c4+0]=vv.x*sc; tile[d][c4+1]=vv.y*sc; tile[d][c4+2]=vv.z*sc; tile[d][c4+3]=vv.w*sc;
  }
  __syncthreads();
  #pragma unroll
  for (int i=0;i<4;i++){
    int kk = r + i*16;
    unsigned int lo = pack2(tile[c4+0][kk], tile[c4+1][kk]);
    unsigned int hi = pack2(tile[c4+2][kk], tile[c4+3][kk]);
    *(uint2*)&Bt[(size_t)(h*64+kk)*1024 + d0 + c4] = make_uint2(lo, hi);
  }
}

// ------ GEMM core: bf16 A,B via gload_lds, pre-swizzled source ------------
// LDS chunk swizzle: chunk' = chunk ^ (row & 3)  (16B chunks, 4 per 64B row)

static __device__ __forceinline__ void gemm_core_bf16(
    const short* __restrict__ A, const short* __restrict__ Bt,
    int bm, int bn, short* As, short* Bs, f32x4 acc[4][4])
{
  int tid = threadIdx.x;
  int w = tid>>6, lane = tid&63;
  int wm = w>>1, wn = w&1;
  int col = lane&15, kg = lane>>4;
  int rs = w*16 + (lane>>2);
  int ch = lane&3;
  int chs = ch ^ (rs & 3);            // pre-swizzled global chunk

  auto stage = [&](int buf, int kt){
    #pragma unroll
    for (int it=0; it<2; ++it){
      int r = rs + it*64;
      gload_lds16(As + buf*4096 + r*32 + ch*8,
                  A + (size_t)(bm*128 + r)*1024 + kt*32 + chs*8);
    }
    #pragma unroll
    for (int it=0; it<2; ++it){
      int r = rs + it*64;
      gload_lds16(Bs + buf*4096 + r*32 + ch*8,
                  Bt + (size_t)(bn*128 + r)*1024 + kt*32 + chs*8);
    }
  };

  const f32x4 fzero = {0.f,0.f,0.f,0.f};
  #pragma unroll
  for (int mf=0; mf<4; ++mf)
    #pragma unroll
    for (int nf=0; nf<4; ++nf)
      acc[mf][nf] = fzero;

  int fbase = col*32 + ((kg ^ (col&3))<<3);   // lane part of fragment addr (shorts)

  stage(0, 0);
  int buf = 0;
  for (int kt=0; kt<32; ++kt){
    __syncthreads();
    if (kt < 31) stage(buf^1, kt+1);
    s16x8 af[4], bfr[4];
    #pragma unroll
    for (int mf=0; mf<4; ++mf)
      af[mf] = *(const s16x8*)(As + buf*4096 + (wm*64 + mf*16)*32 + fbase);
    #pragma unroll
    for (int nf=0; nf<4; ++nf)
      bfr[nf] = *(const s16x8*)(Bs + buf*4096 + (wn*64 + nf*16)*32 + fbase);
    #pragma unroll
    for (int mf=0; mf<4; ++mf)
      #pragma unroll
      for (int nf=0; nf<4; ++nf)
        acc[mf][nf] = mfma16(af[mf], bfr[nf], acc[mf][nf]);
    buf ^= 1;
  }
}

// fused QKV projection: grid 1536 = 64 m-blocks x (3 mats x 8 n-blocks)
// Epilogues:
//   Q -> qp row-major [b*2048+s][1024] (h*64+d)
//   K -> kpT tiled    [(b*16+h)*64+ts][c=8][t=32][j=8]   (ts=s>>5, c=d>>3)
//   V -> vTt tiled    [(b*16+h)*64+ts][c2=4][dv=64][j=8] (c2=(s&31)>>3, j=s&7)
__global__ __launch_bounds__(256,2) void gemm_qkv(short* __restrict__ ws){
  __shared__ __align__(16) short As[2*4096];
  __shared__ __align__(16) short Bs[2*4096];
  int bid = blockIdx.x;
  bid = (bid & 7)*192 + (bid >> 3);          // XCD swizzle (1536 % 8 == 0)
  int bm = bid / 24, bnq = bid % 24;
  int sel = bnq >> 3, bn = bnq & 7;
  const short* A  = ws + (size_t)sel*SZ;
  const short* Bt = ws + 6*SZ + (size_t)sel*WSZ;
  f32x4 acc[4][4];
  gemm_core_bf16(A, Bt, bm, bn, As, Bs, acc);

  int tid = threadIdx.x, w = tid>>6, lane = tid&63;
  int wm=w>>1, wn=w&1, col=lane&15, kg=lane>>4;
  if (sel == 0){
    short* O = ws + 3*SZ;                    // qp row-major
    #pragma unroll
    for (int mf=0; mf<4; ++mf){
      int gr0 = bm*128 + wm*64 + mf*16 + kg*4;
      #pragma unroll
      for (int nf=0; nf<4; ++nf){
        int gc = bn*128 + wn*64 + nf*16 + col;
        #pragma unroll
        for (int r=0; r<4; ++r)
          O[(size_t)(gr0+r)*1024 + gc] = f2bf(acc[mf][nf][r]);
      }
    }
  } else if (sel == 1){
    short* Kt = ws + 4*SZ;                   // kpT tiled [bh*64+ts][c=8][t=32][j=8]
    #pragma unroll
    for (int mf=0; mf<4; ++mf){
      int gr0 = bm*128 + wm*64 + mf*16 + kg*4;
      int b = gr0 >> 11, s0 = gr0 & 2047;
      int ts = s0 >> 5, t0 = s0 & 31;
      #pragma unroll
      for (int nf=0; nf<4; ++nf){
        int gc = bn*128 + wn*64 + nf*16 + col;
        int h = gc >> 6, d = gc & 63;
        size_t base = ((size_t)((b*16+h)*64 + ts))*2048 + (size_t)((d>>3)*32)*8 + (d&7);
        #pragma unroll
        for (int r=0; r<4; ++r)
          Kt[base + (size_t)(t0+r)*8] = f2bf(acc[mf][nf][r]);
      }
    }
  } else {
    short* Vt = ws + 5*SZ;                   // vTt tiled [bh*64+ts][c2=4][dv=64][j=8]
    #pragma unroll
    for (int mf=0; mf<4; ++mf){
      int gr0 = bm*128 + wm*64 + mf*16 + kg*4;
      int b = gr0 >> 11, s0 = gr0 & 2047;
      int ts = s0 >> 5, c2 = (s0 >> 3) & 3, j0 = s0 & 7;
      #pragma unroll
      for (int nf=0; nf<4; ++nf){
        int gc = bn*128 + wn*64 + nf*16 + col;
        int h = gc >> 6, dv = gc & 63;
        unsigned int lo = pack2(acc[mf][nf][0], acc[mf][nf][1]);
        unsigned int hi = pack2(acc[mf][nf][2], acc[mf][nf][3]);
        size_t addr = ((size_t)((b*16+h)*64 + ts))*2048 + (size_t)(c2*64 + dv)*8 + j0;
        *(uint2*)&Vt[addr] = make_uint2(lo, hi);
      }
    }
  }
}

// output projection: concat[8192][1024] x Wout^T + bias -> fp32
__global__ __launch_bounds__(256,2) void gemm_out(const short* __restrict__ cc,
                                                  const short* __restrict__ BtO,
                                                  const float* __restrict__ bias,
                                                  float* __restrict__ out){
  __shared__ __align__(16) short As[2*4096];
  __shared__ __align__(16) short Bs[2*4096];
  int bid = blockIdx.x;
  bid = (bid & 7)*64 + (bid >> 3);           // XCD swizzle (512 % 8 == 0)
  int bm = bid >> 3, bn = bid & 7;
  f32x4 acc[4][4];
  gemm_core_bf16(cc, BtO, bm, bn, As, Bs, acc);

  int tid = threadIdx.x, w=tid>>6, lane=tid&63;
  int wm=w>>1, wn=w&1, col=lane&15, kg=lane>>4;
  #pragma unroll
  for (int nf=0; nf<4; ++nf){
    int gc = bn*128 + wn*64 + nf*16 + col;
    float bb = bias[gc];
    #pragma unroll
    for (int mf=0; mf<4; ++mf){
      int gr0 = bm*128 + wm*64 + mf*16 + kg*4;
      #pragma unroll
      for (int r=0; r<4; ++r)
        out[(size_t)(gr0+r)*1024 + gc] = acc[mf][nf][r] + bb;
    }
  }
}

// ---------------- flash attention (barrier-free, 32 q/wave, 4 waves/SIMD) -
// 32 q/wave, 4 independent waves/block (NO LDS, NO __syncthreads), grid 1024
// -> 4096 waves = 4 independent serial chains per SIMD. Per iter (KVBLK=32):
// issue V frags -> QK (4 mfma32) -> issue K(t+1) frags -> exp2/pack -> PV
// (4 mfma32). Tiled kpT/vTt make every fragment contiguous & coalesced;
// same-block waves march t together so L1 serves the duplicate reads.
// Static-m softmax (exp2 domain, QSCALE folded into Wq).
__global__ __launch_bounds__(256,4) void attn(const short* __restrict__ qp,
                                              const short* __restrict__ kpT,
                                              const short* __restrict__ vTt,
                                              short* __restrict__ cc){
  int bid = blockIdx.x;
  bid = (bid & 7)*128 + (bid >> 3);          // XCD swizzle (1024 % 8 == 0)
  int qb = bid & 15, h = (bid>>4) & 15, b = bid >> 8;
  int bh = b*16 + h;
  int tid = threadIdx.x, w = tid>>6, lane = tid&63;
  int ql = lane & 31, hi = lane >> 5;
  int qbase = qb*128 + w*32;

  const short* qg = qp + ((size_t)(b*2048 + qbase + ql))*1024 + h*64;
  s16x8 qf[4];
  #pragma unroll
  for (int ks=0; ks<4; ++ks)
    qf[ks] = *(const s16x8*)(qg + ks*16 + hi*8);

  const short* kfb = kpT + (size_t)(bh*64)*2048 + hi*256 + ql*8;  // + ks*512
  const short* vfb = vTt + (size_t)(bh*64)*2048 + hi*512 + ql*8;  // + ks2*1024 + dvt*256

  const f32x16 z16 = {0.f,0.f,0.f,0.f,0.f,0.f,0.f,0.f,
                      0.f,0.f,0.f,0.f,0.f,0.f,0.f,0.f};
  f32x16 o0 = z16, o1 = z16;
  float l = 0.f;

  auto packP = [&](f32x16& s, s16x8* pb){
    u32 a0 = pack2(s[0], s[1]),  b0 = pack2(s[2], s[3]);
    u32 c0 = pack2(s[4], s[5]),  d0 = pack2(s[6], s[7]);
    asm("v_permlane32_swap_b32 %0, %1" : "+v"(a0), "+v"(c0));
    asm("v_permlane32_swap_b32 %0, %1" : "+v"(b0), "+v"(d0));
    u32x4 t0v = {a0, b0, c0, d0};
    pb[0] = __builtin_bit_cast(s16x8, t0v);
    u32 a1 = pack2(s[8], s[9]),   b1 = pack2(s[10], s[11]);
    u32 c1 = pack2(s[12], s[13]), d1 = pack2(s[14], s[15]);
    asm("v_permlane32_swap_b32 %0, %1" : "+v"(a1), "+v"(c1));
    asm("v_permlane32_swap_b32 %0, %1" : "+v"(b1), "+v"(d1));
    u32x4 t1v = {a1, b1, c1, d1};
    pb[1] = __builtin_bit_cast(s16x8, t1v);
  };

  s16x8 kf[4];
  #pragma unroll
  for (int ks=0; ks<4; ++ks)
    kf[ks] = *(const s16x8*)(kfb + ks*512);

  for (int ts = 0; ts < 64; ++ts){
    const short* vsrc = vfb + (size_t)ts*2048;
    s16x8 vf0 = *(const s16x8*)(vsrc);          // ks2=0, dvt=0
    s16x8 vf1 = *(const s16x8*)(vsrc + 256);    // ks2=0, dvt=1
    s16x8 vf2 = *(const s16x8*)(vsrc + 1024);   // ks2=1, dvt=0
    s16x8 vf3 = *(const s16x8*)(vsrc + 1280);   // ks2=1, dvt=1

    f32x16 s0 = z16;
    __builtin_amdgcn_s_setprio(1);
    #pragma unroll
    for (int ks=0; ks<4; ++ks)
      s0 = mfma32(kf[ks], qf[ks], s0);
    __builtin_amdgcn_s_setprio(0);

    if (ts < 63){
      const short* ksrc = kfb + (size_t)(ts+1)*2048;
      #pragma unroll
      for (int ks=0; ks<4; ++ks)
        kf[ks] = *(const s16x8*)(ksrc + ks*512);
    }

    f32x2 la = {0.f,0.f}, lb = {0.f,0.f};
    #pragma unroll
    for (int i=0;i<16;i+=4){
      s0[i]   = __builtin_amdgcn_exp2f(s0[i]);
      s0[i+1] = __builtin_amdgcn_exp2f(s0[i+1]);
      s0[i+2] = __builtin_amdgcn_exp2f(s0[i+2]);
      s0[i+3] = __builtin_amdgcn_exp2f(s0[i+3]);
      f32x2 pa = {s0[i], s0[i+1]}, pbv = {s0[i+2], s0[i+3]};
      la += pa; lb += pbv;
    }
    la += lb;
    l += la[0] + la[1];

    s16x8 pb[2];
    packP(s0, pb);

    __builtin_amdgcn_s_setprio(1);
    o0 = mfma32(vf0, pb[0], o0);
    o1 = mfma32(vf1, pb[0], o1);
    o0 = mfma32(vf2, pb[1], o0);
    o1 = mfma32(vf3, pb[1], o1);
    __builtin_amdgcn_s_setprio(0);
  }

  // ---- epilogue: l reduce across lane halves, normalize, store ----
  l += __shfl_xor(l, 32);
  float rcl = 1.0f / l;
  short* og = cc + ((size_t)(b*2048 + qbase + ql))*1024 + h*64;
  #pragma unroll
  for (int s=0; s<4; ++s){
    int dv0 = s*8 + hi*4;
    uint2 w0, w1;
    w0.x = pack2(o0[s*4+0]*rcl, o0[s*4+1]*rcl);
    w0.y = pack2(o0[s*4+2]*rcl, o0[s*4+3]*rcl);
    *(uint2*)&og[dv0] = w0;
    w1.x = pack2(o1[s*4+0]*rcl, o1[s*4+1]*rcl);
    w1.y = pack2(o1[s*4+2]*rcl, o1[s*4+3]*rcl);
    *(uint2*)&og[32 + dv0] = w1;
  }
}

// ---------------- launch ----------------

extern "C" void kernel_launch(void* const* d_in, const int* in_sizes, int n_in,
                              void* d_out, int out_size, void* d_ws, size_t ws_size,
                              hipStream_t stream){
  const float* q  = (const float*)d_in[0];
  const float* k  = (const float*)d_in[1];
  const float* v  = (const float*)d_in[2];
  const float* wq = (const float*)d_in[3];
  const float* wk = (const float*)d_in[4];
  const float* wv = (const float*)d_in[5];
  const float* wo = (const float*)d_in[6];
  const float* bo = (const float*)d_in[7];
  short* ws = (short*)d_ws;
  float* out = (float*)d_out;

  // ws layout (bf16 elems): [0,3SZ) A_q/A_k/A_v (cc reuses [0,SZ) after attn)
  // [3SZ) qp, [4SZ) kpT(tiled), [5SZ) vTt(tiled), [6SZ) BtQ,BtK,BtV,
  // [6SZ+3WSZ) BtO
  size_t needed = (6*SZ + 4*WSZ)*sizeof(short);
  if (ws_size < needed) return;

  convert_misc<<<6400, 256, 0, stream>>>(q, k, v, wo, ws);
  convert_wqkv<<<768, 256, 0, stream>>>(wq, wk, wv, ws);
  gemm_qkv<<<1536, 256, 0, stream>>>(ws);
  attn<<<1024, 256, 0, stream>>>(ws + 3*SZ, ws + 4*SZ, ws + 5*SZ, ws);
  gemm_out<<<512, 256, 0, stream>>>(ws, ws + 6*SZ + 3*WSZ, bo, out);
}

// Round 16
// 197.730 us; speedup vs baseline: 1.0489x; 1.0489x over previous
//
#include <hip/hip_runtime.h>
#include <hip/hip_bf16.h>
#include <stdint.h>

#define DM 1024
#define SZ ((size_t)8192*1024)      // elems of one [8192][1024] matrix (2^23)
#define WSZ ((size_t)1024*1024)     // elems of one [1024][1024] weight

typedef float  f32x2  __attribute__((ext_vector_type(2)));
typedef float  f32x4  __attribute__((ext_vector_type(4)));
typedef float  f32x16 __attribute__((ext_vector_type(16)));
typedef __bf16 bf16x8 __attribute__((ext_vector_type(8)));
typedef __bf16 bf16x2 __attribute__((ext_vector_type(2)));
typedef short  s16x8  __attribute__((ext_vector_type(8)));
typedef unsigned int u32;
typedef unsigned int u32x4 __attribute__((ext_vector_type(4)));

typedef const __attribute__((address_space(1))) void* gas_ptr;
typedef __attribute__((address_space(3))) void* las_ptr;

static __device__ __forceinline__ f32x4 mfma16(s16x8 a, s16x8 b, f32x4 c){
  return __builtin_amdgcn_mfma_f32_16x16x32_bf16(
      __builtin_bit_cast(bf16x8, a), __builtin_bit_cast(bf16x8, b), c, 0, 0, 0);
}
static __device__ __forceinline__ f32x16 mfma32(s16x8 a, s16x8 b, f32x16 c){
  return __builtin_amdgcn_mfma_f32_32x32x16_bf16(
      __builtin_bit_cast(bf16x8, a), __builtin_bit_cast(bf16x8, b), c, 0, 0, 0);
}

// packed f32x2 -> bf16x2 (compiler emits v_cvt_pk_bf16_f32, RNE)
static __device__ __forceinline__ u32 pack2(float a, float b){
  bf16x2 v = { (__bf16)a, (__bf16)b };
  return __builtin_bit_cast(u32, v);
}
static __device__ __forceinline__ short f2bf(float f){
  __bf16 v = (__bf16)f;
  return __builtin_bit_cast(short, v);
}

static __device__ __forceinline__ void gload_lds16(void* l, const void* g){
  __builtin_amdgcn_global_load_lds((gas_ptr)g, (las_ptr)l, 16, 0, 0);
}

#define QSCALE 0.1803368801111444f   /* 0.125 * log2(e): folded into Wq */

// ---------------- conversion kernels ----------------

// q/k/v fp32 -> bf16 at ws[0..3SZ); Wout fp32 -> bf16 at ws[6SZ+3WSZ).
// 16 elems/thread: grid 6400 x 256 x 16 = 3*SZ + WSZ exactly.
__global__ void convert_misc(const float* __restrict__ q, const float* __restrict__ k,
                             const float* __restrict__ v, const float* __restrict__ wo,
                             short* __restrict__ ws){
  size_t c = (size_t)blockIdx.x*blockDim.x + threadIdx.x;   // 16-elem chunk id
  const size_t n16_in = 3*(SZ/16);                          // 3 * 2^19
  const float* src; short* dst;
  if (c < n16_in){
    int s = (int)(c >> 19);                 // SZ/16 = 2^19
    size_t off = c*16 - ((size_t)s << 23);
    src = (s==0 ? q : (s==1 ? k : v)) + off;
    dst = ws + c*16;
  } else {
    size_t off = (c - n16_in)*16;
    src = wo + off;
    dst = ws + 6*SZ + 3*WSZ + off;
  }
  float4 a = *(const float4*)src;
  float4 b = *(const float4*)(src + 4);
  float4 e = *(const float4*)(src + 8);
  float4 f = *(const float4*)(src + 12);
  uint4 o0, o1;
  o0.x = pack2(a.x, a.y); o0.y = pack2(a.z, a.w);
  o0.z = pack2(b.x, b.y); o0.w = pack2(b.z, b.w);
  o1.x = pack2(e.x, e.y); o1.y = pack2(e.z, e.w);
  o1.z = pack2(f.x, f.y); o1.w = pack2(f.z, f.w);
  *(uint4*)dst = o0;
  *(uint4*)(dst + 8) = o1;
}

// Wq/Wk/Wv [16][1024][64] -> Bt[n=h*64+k][d] bf16; Wq scaled by QSCALE
__global__ void convert_wqkv(const float* __restrict__ wq, const float* __restrict__ wk,
                             const float* __restrict__ wv, short* __restrict__ ws){
  __shared__ float tile[64][65];
  int bid = blockIdx.x;
  int sel = bid >> 8;          // 0..2
  int h   = (bid >> 4) & 15;
  int dt  = bid & 15;
  const float* W = sel==0 ? wq : (sel==1 ? wk : wv);
  float sc = sel==0 ? QSCALE : 1.0f;
  short* Bt = ws + 6*SZ + (size_t)sel*WSZ;
  int tid = threadIdx.x;
  int r = tid >> 4, c4 = (tid & 15)*4;
  int d0 = dt*64;
  #pragma unroll
  for (int i=0;i<4;i++){
    int d = r + i*16;
    float4 vv = *(const float4*)&W[(size_t)h*65536 + (size_t)(d0+d)*64 + c4];
    tile[d][c4+0]=vv.x*sc; tile[d][c4+1]=vv.y*sc; tile[d][c4+2]=vv.z*sc; tile[d][c4+3]=vv.w*sc;
  }
  __syncthreads();
  #pragma unroll
  for (int i=0;i<4;i++){
    int kk = r + i*16;
    unsigned int lo = pack2(tile[c4+0][kk], tile[c4+1][kk]);
    unsigned int hi = pack2(tile[c4+2][kk], tile[c4+3][kk]);
    *(uint2*)&Bt[(size_t)(h*64+kk)*1024 + d0 + c4] = make_uint2(lo, hi);
  }
}

// ------ GEMM core: bf16 A,B via gload_lds, pre-swizzled source ------------
// LDS chunk swizzle: chunk' = chunk ^ (row & 3)  (16B chunks, 4 per 64B row)

static __device__ __forceinline__ void gemm_core_bf16(
    const short* __restrict__ A, const short* __restrict__ Bt,
    int bm, int bn, short* As, short* Bs, f32x4 acc[4][4])
{
  int tid = threadIdx.x;
  int w = tid>>6, lane = tid&63;
  int wm = w>>1, wn = w&1;
  int col = lane&15, kg = lane>>4;
  int rs = w*16 + (lane>>2);
  int ch = lane&3;
  int chs = ch ^ (rs & 3);            // pre-swizzled global chunk

  auto stage = [&](int buf, int kt){
    #pragma unroll
    for (int it=0; it<2; ++it){
      int r = rs + it*64;
      gload_lds16(As + buf*4096 + r*32 + ch*8,
                  A + (size_t)(bm*128 + r)*1024 + kt*32 + chs*8);
    }
    #pragma unroll
    for (int it=0; it<2; ++it){
      int r = rs + it*64;
      gload_lds16(Bs + buf*4096 + r*32 + ch*8,
                  Bt + (size_t)(bn*128 + r)*1024 + kt*32 + chs*8);
    }
  };

  const f32x4 fzero = {0.f,0.f,0.f,0.f};
  #pragma unroll
  for (int mf=0; mf<4; ++mf)
    #pragma unroll
    for (int nf=0; nf<4; ++nf)
      acc[mf][nf] = fzero;

  int fbase = col*32 + ((kg ^ (col&3))<<3);   // lane part of fragment addr (shorts)

  stage(0, 0);
  int buf = 0;
  for (int kt=0; kt<32; ++kt){
    __syncthreads();
    if (kt < 31) stage(buf^1, kt+1);
    s16x8 af[4], bfr[4];
    #pragma unroll
    for (int mf=0; mf<4; ++mf)
      af[mf] = *(const s16x8*)(As + buf*4096 + (wm*64 + mf*16)*32 + fbase);
    #pragma unroll
    for (int nf=0; nf<4; ++nf)
      bfr[nf] = *(const s16x8*)(Bs + buf*4096 + (wn*64 + nf*16)*32 + fbase);
    #pragma unroll
    for (int mf=0; mf<4; ++mf)
      #pragma unroll
      for (int nf=0; nf<4; ++nf)
        acc[mf][nf] = mfma16(af[mf], bfr[nf], acc[mf][nf]);
    buf ^= 1;
  }
}

// fused QKV projection: grid 1536 = 64 m-blocks x (3 mats x 8 n-blocks)
// Epilogues:
//   Q -> qp row-major [b*2048+s][1024] (h*64+d)
//   K -> kpT tiled    [(b*16+h)*64+ts][c=8][t=32][j=8]   (ts=s>>5, c=d>>3)
//   V -> vTt tiled    [(b*16+h)*64+ts][c2=4][dv=64][j=8] (c2=(s&31)>>3, j=s&7)
__global__ __launch_bounds__(256,2) void gemm_qkv(short* __restrict__ ws){
  __shared__ __align__(16) short As[2*4096];
  __shared__ __align__(16) short Bs[2*4096];
  int bid = blockIdx.x;
  bid = (bid & 7)*192 + (bid >> 3);          // XCD swizzle (1536 % 8 == 0)
  int bm = bid / 24, bnq = bid % 24;
  int sel = bnq >> 3, bn = bnq & 7;
  const short* A  = ws + (size_t)sel*SZ;
  const short* Bt = ws + 6*SZ + (size_t)sel*WSZ;
  f32x4 acc[4][4];
  gemm_core_bf16(A, Bt, bm, bn, As, Bs, acc);

  int tid = threadIdx.x, w = tid>>6, lane = tid&63;
  int wm=w>>1, wn=w&1, col=lane&15, kg=lane>>4;
  if (sel == 0){
    short* O = ws + 3*SZ;                    // qp row-major
    #pragma unroll
    for (int mf=0; mf<4; ++mf){
      int gr0 = bm*128 + wm*64 + mf*16 + kg*4;
      #pragma unroll
      for (int nf=0; nf<4; ++nf){
        int gc = bn*128 + wn*64 + nf*16 + col;
        #pragma unroll
        for (int r=0; r<4; ++r)
          O[(size_t)(gr0+r)*1024 + gc] = f2bf(acc[mf][nf][r]);
      }
    }
  } else if (sel == 1){
    short* Kt = ws + 4*SZ;                   // kpT tiled [bh*64+ts][c=8][t=32][j=8]
    #pragma unroll
    for (int mf=0; mf<4; ++mf){
      int gr0 = bm*128 + wm*64 + mf*16 + kg*4;
      int b = gr0 >> 11, s0 = gr0 & 2047;
      int ts = s0 >> 5, t0 = s0 & 31;
      #pragma unroll
      for (int nf=0; nf<4; ++nf){
        int gc = bn*128 + wn*64 + nf*16 + col;
        int h = gc >> 6, d = gc & 63;
        size_t base = ((size_t)((b*16+h)*64 + ts))*2048 + (size_t)((d>>3)*32)*8 + (d&7);
        #pragma unroll
        for (int r=0; r<4; ++r)
          Kt[base + (size_t)(t0+r)*8] = f2bf(acc[mf][nf][r]);
      }
    }
  } else {
    short* Vt = ws + 5*SZ;                   // vTt tiled [bh*64+ts][c2=4][dv=64][j=8]
    #pragma unroll
    for (int mf=0; mf<4; ++mf){
      int gr0 = bm*128 + wm*64 + mf*16 + kg*4;
      int b = gr0 >> 11, s0 = gr0 & 2047;
      int ts = s0 >> 5, c2 = (s0 >> 3) & 3, j0 = s0 & 7;
      #pragma unroll
      for (int nf=0; nf<4; ++nf){
        int gc = bn*128 + wn*64 + nf*16 + col;
        int h = gc >> 6, dv = gc & 63;
        unsigned int lo = pack2(acc[mf][nf][0], acc[mf][nf][1]);
        unsigned int hi = pack2(acc[mf][nf][2], acc[mf][nf][3]);
        size_t addr = ((size_t)((b*16+h)*64 + ts))*2048 + (size_t)(c2*64 + dv)*8 + j0;
        *(uint2*)&Vt[addr] = make_uint2(lo, hi);
      }
    }
  }
}

// output projection: concat[8192][1024] x Wout^T + bias -> fp32
__global__ __launch_bounds__(256,2) void gemm_out(const short* __restrict__ cc,
                                                  const short* __restrict__ BtO,
                                                  const float* __restrict__ bias,
                                                  float* __restrict__ out){
  __shared__ __align__(16) short As[2*4096];
  __shared__ __align__(16) short Bs[2*4096];
  int bid = blockIdx.x;
  bid = (bid & 7)*64 + (bid >> 3);           // XCD swizzle (512 % 8 == 0)
  int bm = bid >> 3, bn = bid & 7;
  f32x4 acc[4][4];
  gemm_core_bf16(cc, BtO, bm, bn, As, Bs, acc);

  int tid = threadIdx.x, w=tid>>6, lane=tid&63;
  int wm=w>>1, wn=w&1, col=lane&15, kg=lane>>4;
  #pragma unroll
  for (int nf=0; nf<4; ++nf){
    int gc = bn*128 + wn*64 + nf*16 + col;
    float bb = bias[gc];
    #pragma unroll
    for (int mf=0; mf<4; ++mf){
      int gr0 = bm*128 + wm*64 + mf*16 + kg*4;
      #pragma unroll
      for (int r=0; r<4; ++r)
        out[(size_t)(gr0+r)*1024 + gc] = acc[mf][nf][r] + bb;
    }
  }
}

// ---------------- flash attention (barrier-free, 2-chain ILP) -------------
// 64 q/wave, 4 independent waves/block (NO LDS, NO barriers), grid 512.
// ts unrolled x2 into two named chains A (even tile) and B (odd tile),
// explicitly interleaved: QK_A -> prefK_A -> exp_A -> loadV_B -> QK_B ->
// prefK_B -> pack_A+PV_A -> exp_B+pack_B+PV_B. QK_B (MFMA) overlaps exp_A
// (VALU); PV_A overlaps exp_B: single-wave MFMA||VALU co-issue closes the
// ~25% both-pipes-idle gap seen at 2 waves/SIMD. All accumulators and
// fragment arrays statically indexed (no scratch). Tiled kpT/vTt layouts:
// every fragment load is a contiguous coalesced 1KB read (L1/L2-served).
// Static-m softmax (exp2 domain, QSCALE folded into Wq).
__global__ __launch_bounds__(256,2) void attn(const short* __restrict__ qp,
                                              const short* __restrict__ kpT,
                                              const short* __restrict__ vTt,
                                              short* __restrict__ cc){
  int bid = blockIdx.x;
  bid = (bid & 7)*64 + (bid >> 3);           // XCD swizzle (512 % 8 == 0)
  int qb = bid & 7, h = (bid>>3) & 15, b = bid >> 7;
  int bh = b*16 + h;
  int tid = threadIdx.x, w = tid>>6, lane = tid&63;
  int ql = lane & 31, hi = lane >> 5;
  int qbase = qb*256 + w*64;

  const short* qg = qp + ((size_t)(b*2048 + qbase + ql))*1024 + h*64;
  s16x8 qf[2][4];
  #pragma unroll
  for (int qt=0; qt<2; ++qt)
    #pragma unroll
    for (int ks=0; ks<4; ++ks)
      qf[qt][ks] = *(const s16x8*)(qg + qt*32*1024 + ks*16 + hi*8);

  const short* kfb = kpT + (size_t)(bh*64)*2048 + hi*256 + ql*8;  // + ks*512
  const short* vfb = vTt + (size_t)(bh*64)*2048 + hi*512 + ql*8;  // + ks2*1024 + dvt*256

  const f32x16 z16 = {0.f,0.f,0.f,0.f,0.f,0.f,0.f,0.f,
                      0.f,0.f,0.f,0.f,0.f,0.f,0.f,0.f};
  f32x16 o[2][2] = {{z16, z16}, {z16, z16}};
  float l0 = 0.f, l1 = 0.f;

  auto packP = [&](f32x16& s, s16x8* pb){
    u32 a0 = pack2(s[0], s[1]),  b0 = pack2(s[2], s[3]);
    u32 c0 = pack2(s[4], s[5]),  d0 = pack2(s[6], s[7]);
    asm("v_permlane32_swap_b32 %0, %1" : "+v"(a0), "+v"(c0));
    asm("v_permlane32_swap_b32 %0, %1" : "+v"(b0), "+v"(d0));
    u32x4 t0v = {a0, b0, c0, d0};
    pb[0] = __builtin_bit_cast(s16x8, t0v);
    u32 a1 = pack2(s[8], s[9]),   b1 = pack2(s[10], s[11]);
    u32 c1 = pack2(s[12], s[13]), d1 = pack2(s[14], s[15]);
    asm("v_permlane32_swap_b32 %0, %1" : "+v"(a1), "+v"(c1));
    asm("v_permlane32_swap_b32 %0, %1" : "+v"(b1), "+v"(d1));
    u32x4 t1v = {a1, b1, c1, d1};
    pb[1] = __builtin_bit_cast(s16x8, t1v);
  };
  auto expAcc = [&](f32x16& s, float& l){
    f32x2 la = {0.f,0.f}, lb = {0.f,0.f};
    #pragma unroll
    for (int i=0;i<16;i+=4){
      s[i]   = __builtin_amdgcn_exp2f(s[i]);
      s[i+1] = __builtin_amdgcn_exp2f(s[i+1]);
      s[i+2] = __builtin_amdgcn_exp2f(s[i+2]);
      s[i+3] = __builtin_amdgcn_exp2f(s[i+3]);
      f32x2 pa = {s[i], s[i+1]}, pbv = {s[i+2], s[i+3]};
      la += pa; lb += pbv;
    }
    la += lb;
    l += la[0] + la[1];
  };

  // prologue: K(0) -> kA, K(1) -> kB
  s16x8 kA[4], kB[4];
  #pragma unroll
  for (int ks=0; ks<4; ++ks){
    kA[ks] = *(const s16x8*)(kfb + ks*512);
    kB[ks] = *(const s16x8*)(kfb + 2048 + ks*512);
  }

  for (int ts = 0; ts < 64; ts += 2){
    // ---- load V(ts) for chain A ----
    const short* vsA = vfb + (size_t)ts*2048;
    s16x8 vA0 = *(const s16x8*)(vsA);
    s16x8 vA1 = *(const s16x8*)(vsA + 256);
    s16x8 vA2 = *(const s16x8*)(vsA + 1024);
    s16x8 vA3 = *(const s16x8*)(vsA + 1280);

    // ---- QK_A ----
    f32x16 sA0 = z16, sA1 = z16;
    #pragma unroll
    for (int ks=0; ks<4; ++ks){
      sA0 = mfma32(kA[ks], qf[0][ks], sA0);
      sA1 = mfma32(kA[ks], qf[1][ks], sA1);
    }
    // prefetch K(ts+2) -> kA
    if (ts+2 < 64){
      const short* ksrc = kfb + (size_t)(ts+2)*2048;
      #pragma unroll
      for (int ks=0; ks<4; ++ks)
        kA[ks] = *(const s16x8*)(ksrc + ks*512);
    }

    // ---- exp_A (VALU; overlaps with upcoming QK_B via scheduler) ----
    expAcc(sA0, l0);
    expAcc(sA1, l1);

    // ---- load V(ts+1) for chain B ----
    const short* vsB = vfb + (size_t)(ts+1)*2048;
    s16x8 vB0 = *(const s16x8*)(vsB);
    s16x8 vB1 = *(const s16x8*)(vsB + 256);
    s16x8 vB2 = *(const s16x8*)(vsB + 1024);
    s16x8 vB3 = *(const s16x8*)(vsB + 1280);

    // ---- QK_B (independent of exp_A/pack_A) ----
    f32x16 sB0 = z16, sB1 = z16;
    #pragma unroll
    for (int ks=0; ks<4; ++ks){
      sB0 = mfma32(kB[ks], qf[0][ks], sB0);
      sB1 = mfma32(kB[ks], qf[1][ks], sB1);
    }
    // prefetch K(ts+3) -> kB
    if (ts+3 < 64){
      const short* ksrc = kfb + (size_t)(ts+3)*2048;
      #pragma unroll
      for (int ks=0; ks<4; ++ks)
        kB[ks] = *(const s16x8*)(ksrc + ks*512);
    }

    // ---- pack_A + PV_A (PV_A overlaps exp_B) ----
    s16x8 pA0[2], pA1[2];
    packP(sA0, pA0);
    packP(sA1, pA1);
    o[0][0] = mfma32(vA0, pA0[0], o[0][0]);
    o[1][0] = mfma32(vA0, pA1[0], o[1][0]);
    o[0][1] = mfma32(vA1, pA0[0], o[0][1]);
    o[1][1] = mfma32(vA1, pA1[0], o[1][1]);
    o[0][0] = mfma32(vA2, pA0[1], o[0][0]);
    o[1][0] = mfma32(vA2, pA1[1], o[1][0]);
    o[0][1] = mfma32(vA3, pA0[1], o[0][1]);
    o[1][1] = mfma32(vA3, pA1[1], o[1][1]);

    // ---- exp_B + pack_B + PV_B ----
    expAcc(sB0, l0);
    expAcc(sB1, l1);
    s16x8 pB0[2], pB1[2];
    packP(sB0, pB0);
    packP(sB1, pB1);
    o[0][0] = mfma32(vB0, pB0[0], o[0][0]);
    o[1][0] = mfma32(vB0, pB1[0], o[1][0]);
    o[0][1] = mfma32(vB1, pB0[0], o[0][1]);
    o[1][1] = mfma32(vB1, pB1[0], o[1][1]);
    o[0][0] = mfma32(vB2, pB0[1], o[0][0]);
    o[1][0] = mfma32(vB2, pB1[1], o[1][0]);
    o[0][1] = mfma32(vB3, pB0[1], o[0][1]);
    o[1][1] = mfma32(vB3, pB1[1], o[1][1]);
  }

  // ---- epilogue: l reduce across lane halves, normalize, store ----
  l0 += __shfl_xor(l0, 32);
  l1 += __shfl_xor(l1, 32);
  float rc0 = 1.0f / l0, rc1 = 1.0f / l1;
  #pragma unroll
  for (int qt=0; qt<2; ++qt){
    float rcl = qt ? rc1 : rc0;
    short* og = cc + ((size_t)(b*2048 + qbase + qt*32 + ql))*1024 + h*64;
    #pragma unroll
    for (int dvt=0; dvt<2; ++dvt){
      #pragma unroll
      for (int s=0; s<4; ++s){
        int dv0 = dvt*32 + s*8 + hi*4;
        uint2 wd;
        wd.x = pack2(o[qt][dvt][s*4+0]*rcl, o[qt][dvt][s*4+1]*rcl);
        wd.y = pack2(o[qt][dvt][s*4+2]*rcl, o[qt][dvt][s*4+3]*rcl);
        *(uint2*)&og[dv0] = wd;
      }
    }
  }
}

// ---------------- launch ----------------

extern "C" void kernel_launch(void* const* d_in, const int* in_sizes, int n_in,
                              void* d_out, int out_size, void* d_ws, size_t ws_size,
                              hipStream_t stream){
  const float* q  = (const float*)d_in[0];
  const float* k  = (const float*)d_in[1];
  const float* v  = (const float*)d_in[2];
  const float* wq = (const float*)d_in[3];
  const float* wk = (const float*)d_in[4];
  const float* wv = (const float*)d_in[5];
  const float* wo = (const float*)d_in[6];
  const float* bo = (const float*)d_in[7];
  short* ws = (short*)d_ws;
  float* out = (float*)d_out;

  // ws layout (bf16 elems): [0,3SZ) A_q/A_k/A_v (cc reuses [0,SZ) after attn)
  // [3SZ) qp, [4SZ) kpT(tiled), [5SZ) vTt(tiled), [6SZ) BtQ,BtK,BtV,
  // [6SZ+3WSZ) BtO
  size_t needed = (6*SZ + 4*WSZ)*sizeof(short);
  if (ws_size < needed) return;

  convert_misc<<<6400, 256, 0, stream>>>(q, k, v, wo, ws);
  convert_wqkv<<<768, 256, 0, stream>>>(wq, wk, wv, ws);
  gemm_qkv<<<1536, 256, 0, stream>>>(ws);
  attn<<<512, 256, 0, stream>>>(ws + 3*SZ, ws + 4*SZ, ws + 5*SZ, ws);
  gemm_out<<<512, 256, 0, stream>>>(ws, ws + 6*SZ + 3*WSZ, bo, out);
}

// Round 17
// 195.664 us; speedup vs baseline: 1.0600x; 1.0106x over previous
//
#include <hip/hip_runtime.h>
#include <hip/hip_bf16.h>
#include <stdint.h>

#define DM 1024
#define SZ ((size_t)8192*1024)      // elems of one [8192][1024] matrix (2^23)
#define WSZ ((size_t)1024*1024)     // elems of one [1024][1024] weight

typedef float  f32x2  __attribute__((ext_vector_type(2)));
typedef float  f32x4  __attribute__((ext_vector_type(4)));
typedef float  f32x16 __attribute__((ext_vector_type(16)));
typedef __bf16 bf16x8 __attribute__((ext_vector_type(8)));
typedef __bf16 bf16x2 __attribute__((ext_vector_type(2)));
typedef short  s16x8  __attribute__((ext_vector_type(8)));
typedef unsigned int u32;
typedef unsigned int u32x4 __attribute__((ext_vector_type(4)));

typedef const __attribute__((address_space(1))) void* gas_ptr;
typedef __attribute__((address_space(3))) void* las_ptr;

static __device__ __forceinline__ f32x4 mfma16(s16x8 a, s16x8 b, f32x4 c){
  return __builtin_amdgcn_mfma_f32_16x16x32_bf16(
      __builtin_bit_cast(bf16x8, a), __builtin_bit_cast(bf16x8, b), c, 0, 0, 0);
}
static __device__ __forceinline__ f32x16 mfma32(s16x8 a, s16x8 b, f32x16 c){
  return __builtin_amdgcn_mfma_f32_32x32x16_bf16(
      __builtin_bit_cast(bf16x8, a), __builtin_bit_cast(bf16x8, b), c, 0, 0, 0);
}

// packed f32x2 -> bf16x2 (compiler emits v_cvt_pk_bf16_f32, RNE)
static __device__ __forceinline__ u32 pack2(float a, float b){
  bf16x2 v = { (__bf16)a, (__bf16)b };
  return __builtin_bit_cast(u32, v);
}
static __device__ __forceinline__ short f2bf(float f){
  __bf16 v = (__bf16)f;
  return __builtin_bit_cast(short, v);
}

static __device__ __forceinline__ void gload_lds16(void* l, const void* g){
  __builtin_amdgcn_global_load_lds((gas_ptr)g, (las_ptr)l, 16, 0, 0);
}

#define QSCALE 0.1803368801111444f   /* 0.125 * log2(e): folded into Wq */

// ---------------- conversion (merged) ----------------
// blocks [0,6400): q/k/v fp32 -> bf16 at ws[0..3SZ); Wout -> ws[6SZ+3WSZ)
//                  (16 elems/thread, exact cover 3*SZ + WSZ)
// blocks [6400,7168): Wq/Wk/Wv [16][1024][64] -> Bt[n=h*64+k][d] bf16
//                  (Wq scaled by QSCALE), 768 blocks
__global__ void convert_all(const float* __restrict__ q, const float* __restrict__ k,
                            const float* __restrict__ v, const float* __restrict__ wo,
                            const float* __restrict__ wq, const float* __restrict__ wk,
                            const float* __restrict__ wv, short* __restrict__ ws){
  __shared__ float tile[64][65];
  int blk = blockIdx.x;
  int tid = threadIdx.x;
  if (blk < 6400){
    size_t c = (size_t)blk*blockDim.x + tid;              // 16-elem chunk id
    const size_t n16_in = 3*(SZ/16);                      // 3 * 2^19
    const float* src; short* dst;
    if (c < n16_in){
      int s = (int)(c >> 19);               // SZ/16 = 2^19
      size_t off = c*16 - ((size_t)s << 23);
      src = (s==0 ? q : (s==1 ? k : v)) + off;
      dst = ws + c*16;
    } else {
      size_t off = (c - n16_in)*16;
      src = wo + off;
      dst = ws + 6*SZ + 3*WSZ + off;
    }
    float4 a = *(const float4*)src;
    float4 b = *(const float4*)(src + 4);
    float4 e = *(const float4*)(src + 8);
    float4 f = *(const float4*)(src + 12);
    uint4 o0, o1;
    o0.x = pack2(a.x, a.y); o0.y = pack2(a.z, a.w);
    o0.z = pack2(b.x, b.y); o0.w = pack2(b.z, b.w);
    o1.x = pack2(e.x, e.y); o1.y = pack2(e.z, e.w);
    o1.z = pack2(f.x, f.y); o1.w = pack2(f.z, f.w);
    *(uint4*)dst = o0;
    *(uint4*)(dst + 8) = o1;
    return;
  }
  int bid = blk - 6400;
  int sel = bid >> 8;          // 0..2
  int h   = (bid >> 4) & 15;
  int dt  = bid & 15;
  const float* W = sel==0 ? wq : (sel==1 ? wk : wv);
  float sc = sel==0 ? QSCALE : 1.0f;
  short* Bt = ws + 6*SZ + (size_t)sel*WSZ;
  int r = tid >> 4, c4 = (tid & 15)*4;
  int d0 = dt*64;
  #pragma unroll
  for (int i=0;i<4;i++){
    int d = r + i*16;
    float4 vv = *(const float4*)&W[(size_t)h*65536 + (size_t)(d0+d)*64 + c4];
    tile[d][c4+0]=vv.x*sc; tile[d][c4+1]=vv.y*sc; tile[d][c4+2]=vv.z*sc; tile[d][c4+3]=vv.w*sc;
  }
  __syncthreads();
  #pragma unroll
  for (int i=0;i<4;i++){
    int kk = r + i*16;
    unsigned int lo = pack2(tile[c4+0][kk], tile[c4+1][kk]);
    unsigned int hi = pack2(tile[c4+2][kk], tile[c4+3][kk]);
    *(uint2*)&Bt[(size_t)(h*64+kk)*1024 + d0 + c4] = make_uint2(lo, hi);
  }
}

// ------ GEMM core: bf16 A,B via gload_lds, pre-swizzled source ------------
// LDS chunk swizzle: chunk' = chunk ^ (row & 3)  (16B chunks, 4 per 64B row)

static __device__ __forceinline__ void gemm_core_bf16(
    const short* __restrict__ A, const short* __restrict__ Bt,
    int bm, int bn, short* As, short* Bs, f32x4 acc[4][4])
{
  int tid = threadIdx.x;
  int w = tid>>6, lane = tid&63;
  int wm = w>>1, wn = w&1;
  int col = lane&15, kg = lane>>4;
  int rs = w*16 + (lane>>2);
  int ch = lane&3;
  int chs = ch ^ (rs & 3);            // pre-swizzled global chunk

  auto stage = [&](int buf, int kt){
    #pragma unroll
    for (int it=0; it<2; ++it){
      int r = rs + it*64;
      gload_lds16(As + buf*4096 + r*32 + ch*8,
                  A + (size_t)(bm*128 + r)*1024 + kt*32 + chs*8);
    }
    #pragma unroll
    for (int it=0; it<2; ++it){
      int r = rs + it*64;
      gload_lds16(Bs + buf*4096 + r*32 + ch*8,
                  Bt + (size_t)(bn*128 + r)*1024 + kt*32 + chs*8);
    }
  };

  const f32x4 fzero = {0.f,0.f,0.f,0.f};
  #pragma unroll
  for (int mf=0; mf<4; ++mf)
    #pragma unroll
    for (int nf=0; nf<4; ++nf)
      acc[mf][nf] = fzero;

  int fbase = col*32 + ((kg ^ (col&3))<<3);   // lane part of fragment addr (shorts)

  stage(0, 0);
  int buf = 0;
  for (int kt=0; kt<32; ++kt){
    __syncthreads();
    if (kt < 31) stage(buf^1, kt+1);
    s16x8 af[4], bfr[4];
    #pragma unroll
    for (int mf=0; mf<4; ++mf)
      af[mf] = *(const s16x8*)(As + buf*4096 + (wm*64 + mf*16)*32 + fbase);
    #pragma unroll
    for (int nf=0; nf<4; ++nf)
      bfr[nf] = *(const s16x8*)(Bs + buf*4096 + (wn*64 + nf*16)*32 + fbase);
    #pragma unroll
    for (int mf=0; mf<4; ++mf)
      #pragma unroll
      for (int nf=0; nf<4; ++nf)
        acc[mf][nf] = mfma16(af[mf], bfr[nf], acc[mf][nf]);
    buf ^= 1;
  }
}

// fused QKV projection: grid 1536 = 64 m-blocks x (3 mats x 8 n-blocks)
// 3 blocks/CU residency (launch_bounds 3): third block covers the barrier
// drain stall of the other two.
// Epilogues:
//   Q -> qp row-major [b*2048+s][1024] (h*64+d)
//   K -> kpT tiled    [(b*16+h)*64+ts][c=8][t=32][j=8]   (ts=s>>5, c=d>>3)
//   V -> vTt tiled    [(b*16+h)*64+ts][c2=4][dv=64][j=8] (c2=(s&31)>>3, j=s&7)
__global__ __launch_bounds__(256,3) void gemm_qkv(short* __restrict__ ws){
  __shared__ __align__(16) short As[2*4096];
  __shared__ __align__(16) short Bs[2*4096];
  int bid = blockIdx.x;
  bid = (bid & 7)*192 + (bid >> 3);          // XCD swizzle (1536 % 8 == 0)
  int bm = bid / 24, bnq = bid % 24;
  int sel = bnq >> 3, bn = bnq & 7;
  const short* A  = ws + (size_t)sel*SZ;
  const short* Bt = ws + 6*SZ + (size_t)sel*WSZ;
  f32x4 acc[4][4];
  gemm_core_bf16(A, Bt, bm, bn, As, Bs, acc);

  int tid = threadIdx.x, w = tid>>6, lane = tid&63;
  int wm=w>>1, wn=w&1, col=lane&15, kg=lane>>4;
  if (sel == 0){
    short* O = ws + 3*SZ;                    // qp row-major
    #pragma unroll
    for (int mf=0; mf<4; ++mf){
      int gr0 = bm*128 + wm*64 + mf*16 + kg*4;
      #pragma unroll
      for (int nf=0; nf<4; ++nf){
        int gc = bn*128 + wn*64 + nf*16 + col;
        #pragma unroll
        for (int r=0; r<4; ++r)
          O[(size_t)(gr0+r)*1024 + gc] = f2bf(acc[mf][nf][r]);
      }
    }
  } else if (sel == 1){
    short* Kt = ws + 4*SZ;                   // kpT tiled [bh*64+ts][c=8][t=32][j=8]
    #pragma unroll
    for (int mf=0; mf<4; ++mf){
      int gr0 = bm*128 + wm*64 + mf*16 + kg*4;
      int b = gr0 >> 11, s0 = gr0 & 2047;
      int ts = s0 >> 5, t0 = s0 & 31;
      #pragma unroll
      for (int nf=0; nf<4; ++nf){
        int gc = bn*128 + wn*64 + nf*16 + col;
        int h = gc >> 6, d = gc & 63;
        size_t base = ((size_t)((b*16+h)*64 + ts))*2048 + (size_t)((d>>3)*32)*8 + (d&7);
        #pragma unroll
        for (int r=0; r<4; ++r)
          Kt[base + (size_t)(t0+r)*8] = f2bf(acc[mf][nf][r]);
      }
    }
  } else {
    short* Vt = ws + 5*SZ;                   // vTt tiled [bh*64+ts][c2=4][dv=64][j=8]
    #pragma unroll
    for (int mf=0; mf<4; ++mf){
      int gr0 = bm*128 + wm*64 + mf*16 + kg*4;
      int b = gr0 >> 11, s0 = gr0 & 2047;
      int ts = s0 >> 5, c2 = (s0 >> 3) & 3, j0 = s0 & 7;
      #pragma unroll
      for (int nf=0; nf<4; ++nf){
        int gc = bn*128 + wn*64 + nf*16 + col;
        int h = gc >> 6, dv = gc & 63;
        unsigned int lo = pack2(acc[mf][nf][0], acc[mf][nf][1]);
        unsigned int hi = pack2(acc[mf][nf][2], acc[mf][nf][3]);
        size_t addr = ((size_t)((b*16+h)*64 + ts))*2048 + (size_t)(c2*64 + dv)*8 + j0;
        *(uint2*)&Vt[addr] = make_uint2(lo, hi);
      }
    }
  }
}

// output projection: concat[8192][1024] x Wout^T + bias -> fp32
__global__ __launch_bounds__(256,2) void gemm_out(const short* __restrict__ cc,
                                                  const short* __restrict__ BtO,
                                                  const float* __restrict__ bias,
                                                  float* __restrict__ out){
  __shared__ __align__(16) short As[2*4096];
  __shared__ __align__(16) short Bs[2*4096];
  int bid = blockIdx.x;
  bid = (bid & 7)*64 + (bid >> 3);           // XCD swizzle (512 % 8 == 0)
  int bm = bid >> 3, bn = bid & 7;
  f32x4 acc[4][4];
  gemm_core_bf16(cc, BtO, bm, bn, As, Bs, acc);

  int tid = threadIdx.x, w=tid>>6, lane=tid&63;
  int wm=w>>1, wn=w&1, col=lane&15, kg=lane>>4;
  #pragma unroll
  for (int nf=0; nf<4; ++nf){
    int gc = bn*128 + wn*64 + nf*16 + col;
    float bb = bias[gc];
    #pragma unroll
    for (int mf=0; mf<4; ++mf){
      int gr0 = bm*128 + wm*64 + mf*16 + kg*4;
      #pragma unroll
      for (int r=0; r<4; ++r)
        out[(size_t)(gr0+r)*1024 + gc] = acc[mf][nf][r] + bb;
    }
  }
}

// ---------------- flash attention (barrier-free, 2-chain ILP) -------------
// 64 q/wave, 4 independent waves/block (NO LDS, NO barriers), grid 512.
// ts unrolled x2 into two named chains A/B, explicitly interleaved so QK_B
// (MFMA) overlaps exp_A (VALU) and PV_A overlaps exp_B. Tiled kpT/vTt
// layouts: every fragment load is a contiguous coalesced 1KB read.
// Static-m softmax (exp2 domain, QSCALE folded into Wq).
__global__ __launch_bounds__(256,2) void attn(const short* __restrict__ qp,
                                              const short* __restrict__ kpT,
                                              const short* __restrict__ vTt,
                                              short* __restrict__ cc){
  int bid = blockIdx.x;
  bid = (bid & 7)*64 + (bid >> 3);           // XCD swizzle (512 % 8 == 0)
  int qb = bid & 7, h = (bid>>3) & 15, b = bid >> 7;
  int bh = b*16 + h;
  int tid = threadIdx.x, w = tid>>6, lane = tid&63;
  int ql = lane & 31, hi = lane >> 5;
  int qbase = qb*256 + w*64;

  const short* qg = qp + ((size_t)(b*2048 + qbase + ql))*1024 + h*64;
  s16x8 qf[2][4];
  #pragma unroll
  for (int qt=0; qt<2; ++qt)
    #pragma unroll
    for (int ks=0; ks<4; ++ks)
      qf[qt][ks] = *(const s16x8*)(qg + qt*32*1024 + ks*16 + hi*8);

  const short* kfb = kpT + (size_t)(bh*64)*2048 + hi*256 + ql*8;  // + ks*512
  const short* vfb = vTt + (size_t)(bh*64)*2048 + hi*512 + ql*8;  // + ks2*1024 + dvt*256

  const f32x16 z16 = {0.f,0.f,0.f,0.f,0.f,0.f,0.f,0.f,
                      0.f,0.f,0.f,0.f,0.f,0.f,0.f,0.f};
  f32x16 o[2][2] = {{z16, z16}, {z16, z16}};
  float l0 = 0.f, l1 = 0.f;

  auto packP = [&](f32x16& s, s16x8* pb){
    u32 a0 = pack2(s[0], s[1]),  b0 = pack2(s[2], s[3]);
    u32 c0 = pack2(s[4], s[5]),  d0 = pack2(s[6], s[7]);
    asm("v_permlane32_swap_b32 %0, %1" : "+v"(a0), "+v"(c0));
    asm("v_permlane32_swap_b32 %0, %1" : "+v"(b0), "+v"(d0));
    u32x4 t0v = {a0, b0, c0, d0};
    pb[0] = __builtin_bit_cast(s16x8, t0v);
    u32 a1 = pack2(s[8], s[9]),   b1 = pack2(s[10], s[11]);
    u32 c1 = pack2(s[12], s[13]), d1 = pack2(s[14], s[15]);
    asm("v_permlane32_swap_b32 %0, %1" : "+v"(a1), "+v"(c1));
    asm("v_permlane32_swap_b32 %0, %1" : "+v"(b1), "+v"(d1));
    u32x4 t1v = {a1, b1, c1, d1};
    pb[1] = __builtin_bit_cast(s16x8, t1v);
  };
  auto expAcc = [&](f32x16& s, float& l){
    f32x2 la = {0.f,0.f}, lb = {0.f,0.f};
    #pragma unroll
    for (int i=0;i<16;i+=4){
      s[i]   = __builtin_amdgcn_exp2f(s[i]);
      s[i+1] = __builtin_amdgcn_exp2f(s[i+1]);
      s[i+2] = __builtin_amdgcn_exp2f(s[i+2]);
      s[i+3] = __builtin_amdgcn_exp2f(s[i+3]);
      f32x2 pa = {s[i], s[i+1]}, pbv = {s[i+2], s[i+3]};
      la += pa; lb += pbv;
    }
    la += lb;
    l += la[0] + la[1];
  };

  // prologue: K(0) -> kA, K(1) -> kB
  s16x8 kA[4], kB[4];
  #pragma unroll
  for (int ks=0; ks<4; ++ks){
    kA[ks] = *(const s16x8*)(kfb + ks*512);
    kB[ks] = *(const s16x8*)(kfb + 2048 + ks*512);
  }

  for (int ts = 0; ts < 64; ts += 2){
    const short* vsA = vfb + (size_t)ts*2048;
    s16x8 vA0 = *(const s16x8*)(vsA);
    s16x8 vA1 = *(const s16x8*)(vsA + 256);
    s16x8 vA2 = *(const s16x8*)(vsA + 1024);
    s16x8 vA3 = *(const s16x8*)(vsA + 1280);

    f32x16 sA0 = z16, sA1 = z16;
    #pragma unroll
    for (int ks=0; ks<4; ++ks){
      sA0 = mfma32(kA[ks], qf[0][ks], sA0);
      sA1 = mfma32(kA[ks], qf[1][ks], sA1);
    }
    if (ts+2 < 64){
      const short* ksrc = kfb + (size_t)(ts+2)*2048;
      #pragma unroll
      for (int ks=0; ks<4; ++ks)
        kA[ks] = *(const s16x8*)(ksrc + ks*512);
    }

    expAcc(sA0, l0);
    expAcc(sA1, l1);

    const short* vsB = vfb + (size_t)(ts+1)*2048;
    s16x8 vB0 = *(const s16x8*)(vsB);
    s16x8 vB1 = *(const s16x8*)(vsB + 256);
    s16x8 vB2 = *(const s16x8*)(vsB + 1024);
    s16x8 vB3 = *(const s16x8*)(vsB + 1280);

    f32x16 sB0 = z16, sB1 = z16;
    #pragma unroll
    for (int ks=0; ks<4; ++ks){
      sB0 = mfma32(kB[ks], qf[0][ks], sB0);
      sB1 = mfma32(kB[ks], qf[1][ks], sB1);
    }
    if (ts+3 < 64){
      const short* ksrc = kfb + (size_t)(ts+3)*2048;
      #pragma unroll
      for (int ks=0; ks<4; ++ks)
        kB[ks] = *(const s16x8*)(ksrc + ks*512);
    }

    s16x8 pA0[2], pA1[2];
    packP(sA0, pA0);
    packP(sA1, pA1);
    o[0][0] = mfma32(vA0, pA0[0], o[0][0]);
    o[1][0] = mfma32(vA0, pA1[0], o[1][0]);
    o[0][1] = mfma32(vA1, pA0[0], o[0][1]);
    o[1][1] = mfma32(vA1, pA1[0], o[1][1]);
    o[0][0] = mfma32(vA2, pA0[1], o[0][0]);
    o[1][0] = mfma32(vA2, pA1[1], o[1][0]);
    o[0][1] = mfma32(vA3, pA0[1], o[0][1]);
    o[1][1] = mfma32(vA3, pA1[1], o[1][1]);

    expAcc(sB0, l0);
    expAcc(sB1, l1);
    s16x8 pB0[2], pB1[2];
    packP(sB0, pB0);
    packP(sB1, pB1);
    o[0][0] = mfma32(vB0, pB0[0], o[0][0]);
    o[1][0] = mfma32(vB0, pB1[0], o[1][0]);
    o[0][1] = mfma32(vB1, pB0[0], o[0][1]);
    o[1][1] = mfma32(vB1, pB1[0], o[1][1]);
    o[0][0] = mfma32(vB2, pB0[1], o[0][0]);
    o[1][0] = mfma32(vB2, pB1[1], o[1][0]);
    o[0][1] = mfma32(vB3, pB0[1], o[0][1]);
    o[1][1] = mfma32(vB3, pB1[1], o[1][1]);
  }

  // ---- epilogue: l reduce across lane halves, normalize, store ----
  l0 += __shfl_xor(l0, 32);
  l1 += __shfl_xor(l1, 32);
  float rc0 = 1.0f / l0, rc1 = 1.0f / l1;
  #pragma unroll
  for (int qt=0; qt<2; ++qt){
    float rcl = qt ? rc1 : rc0;
    short* og = cc + ((size_t)(b*2048 + qbase + qt*32 + ql))*1024 + h*64;
    #pragma unroll
    for (int dvt=0; dvt<2; ++dvt){
      #pragma unroll
      for (int s=0; s<4; ++s){
        int dv0 = dvt*32 + s*8 + hi*4;
        uint2 wd;
        wd.x = pack2(o[qt][dvt][s*4+0]*rcl, o[qt][dvt][s*4+1]*rcl);
        wd.y = pack2(o[qt][dvt][s*4+2]*rcl, o[qt][dvt][s*4+3]*rcl);
        *(uint2*)&og[dv0] = wd;
      }
    }
  }
}

// ---------------- launch ----------------

extern "C" void kernel_launch(void* const* d_in, const int* in_sizes, int n_in,
                              void* d_out, int out_size, void* d_ws, size_t ws_size,
                              hipStream_t stream){
  const float* q  = (const float*)d_in[0];
  const float* k  = (const float*)d_in[1];
  const float* v  = (const float*)d_in[2];
  const float* wq = (const float*)d_in[3];
  const float* wk = (const float*)d_in[4];
  const float* wv = (const float*)d_in[5];
  const float* wo = (const float*)d_in[6];
  const float* bo = (const float*)d_in[7];
  short* ws = (short*)d_ws;
  float* out = (float*)d_out;

  // ws layout (bf16 elems): [0,3SZ) A_q/A_k/A_v (cc reuses [0,SZ) after attn)
  // [3SZ) qp, [4SZ) kpT(tiled), [5SZ) vTt(tiled), [6SZ) BtQ,BtK,BtV,
  // [6SZ+3WSZ) BtO
  size_t needed = (6*SZ + 4*WSZ)*sizeof(short);
  if (ws_size < needed) return;

  convert_all<<<7168, 256, 0, stream>>>(q, k, v, wo, wq, wk, wv, ws);
  gemm_qkv<<<1536, 256, 0, stream>>>(ws);
  attn<<<512, 256, 0, stream>>>(ws + 3*SZ, ws + 4*SZ, ws + 5*SZ, ws);
  gemm_out<<<512, 256, 0, stream>>>(ws, ws + 6*SZ + 3*WSZ, bo, out);
}